// Round 1
// baseline (322.024 us; speedup 1.0000x reference)
//
#include <hip/hip_runtime.h>
#include <stdint.h>

// ---- problem constants ----
#define Tn   2048
#define Cn   2048
#define Hn   32
#define KVHn 8
#define Dn   64
#define MR   4096   // B*T
#define NQKV 3072   // 2048 q | 512 k | 512 v
#define KD   2048

typedef __attribute__((ext_vector_type(4))) float fx4;
typedef __attribute__((ext_vector_type(8))) short frag8;

#define MFMA(a,b,c) __builtin_amdgcn_mfma_f32_16x16x32_bf16((a),(b),(c),0,0,0)

struct __align__(16) U16x8 { unsigned short s[8]; };

__device__ __forceinline__ unsigned short f2bf(float x){
  union { float f; unsigned u; } v; v.f = x;
  return (unsigned short)((v.u + 0x7FFFu + ((v.u >> 16) & 1u)) >> 16);
}
__device__ __forceinline__ float bf2f(unsigned short h){
  union { unsigned u; float f; } v; v.u = ((unsigned)h) << 16; return v.f;
}

typedef const __attribute__((address_space(1))) void cas1_void;
typedef __attribute__((address_space(3))) void as3_void;
__device__ __forceinline__ void gld16(const void* g, void* l){
  __builtin_amdgcn_global_load_lds((cas1_void*)g, (as3_void*)l, 16, 0, 0);
}

// ---- fp32 -> bf16 convert (vectorized) ----
__global__ __launch_bounds__(256) void k_cvt(const float* __restrict__ in,
                                             unsigned short* __restrict__ out){
  size_t i = (size_t)blockIdx.x * 256 + threadIdx.x;
  float4 v = *(const float4*)(in + i * 4);
  ushort4 o; o.x = f2bf(v.x); o.y = f2bf(v.y); o.z = f2bf(v.z); o.w = f2bf(v.w);
  *(ushort4*)(out + i * 4) = o;
}

// ---- transpose + convert weights: out[n][k] (bf16) = W[k][n] (f32) ----
// n0<2048 -> W0 (ld 2048), n0<2560 -> W1 (ld 512), else W2 (ld 512)
__global__ __launch_bounds__(256) void k_transW(const float* __restrict__ W0,
                                                const float* __restrict__ W1,
                                                const float* __restrict__ W2,
                                                unsigned short* __restrict__ out){
  __shared__ float tile[64][65];
  int n0 = blockIdx.x * 64, k0 = blockIdx.y * 64;
  const float* src; int col0, ld;
  if (n0 < 2048)      { src = W0; col0 = n0;        ld = 2048; }
  else if (n0 < 2560) { src = W1; col0 = n0 - 2048; ld = 512;  }
  else                { src = W2; col0 = n0 - 2560; ld = 512;  }
  int t = threadIdx.x;
  int r = t >> 2, cc = (t & 3) << 4;
  const float* p = src + (size_t)(k0 + r) * ld + col0 + cc;
  #pragma unroll
  for (int j = 0; j < 16; j += 4) {
    float4 v = *(const float4*)(p + j);
    tile[r][cc + j + 0] = v.x; tile[r][cc + j + 1] = v.y;
    tile[r][cc + j + 2] = v.z; tile[r][cc + j + 3] = v.w;
  }
  __syncthreads();
  int n = t >> 2, kc = (t & 3) << 4;
  unsigned short* q = out + (size_t)(n0 + n) * 2048 + k0 + kc;
  U16x8 o0, o1;
  #pragma unroll
  for (int j = 0; j < 8; ++j) o0.s[j] = f2bf(tile[kc + j][n]);
  #pragma unroll
  for (int j = 0; j < 8; ++j) o1.s[j] = f2bf(tile[kc + 8 + j][n]);
  *(U16x8*)(q) = o0;
  *(U16x8*)(q + 8) = o1;
}

// ---- RoPE cos/sin table: [2048][32] each ----
__global__ __launch_bounds__(256) void k_ropetab(float* __restrict__ ct, float* __restrict__ st){
  int i = blockIdx.x * 256 + threadIdx.x;
  int tp = i >> 5, d = i & 31;
  float inv = powf(10000.0f, -(float)d * (1.0f/32.0f));
  float fr = (float)tp * inv;
  ct[i] = cosf(fr); st[i] = sinf(fr);
}

// ---- m97-style GEMM: C[M][N] = A[M][K] * Bt[N][K]^T  (bf16 in, fp32 acc) ----
template<int OUT_BF16>
__global__ __launch_bounds__(256) void k_gemm(const unsigned short* __restrict__ A,
                                              const unsigned short* __restrict__ Bt,
                                              void* __restrict__ Cp,
                                              int M, int N, int K){
  __shared__ unsigned short As[128 * 64];
  __shared__ unsigned short Bs[128 * 64];
  int tid = threadIdx.x;
  int m0 = blockIdx.y * 128, n0 = blockIdx.x * 128;
  int w = tid >> 6, ln = tid & 63, lr = ln & 15, lg = ln >> 4;
  int wm = (w >> 1) * 64, wn = (w & 1) * 64;
  fx4 acc[4][4];
  #pragma unroll
  for (int i = 0; i < 4; ++i)
    #pragma unroll
    for (int j = 0; j < 4; ++j) acc[i][j] = (fx4){0.f,0.f,0.f,0.f};
  int steps = K >> 6;
  for (int kt = 0; kt < steps; ++kt) {
    int kb = kt << 6;
    #pragma unroll
    for (int it = 0; it < 4; ++it) {
      int nch = it * 256 + tid;
      int r = nch >> 3, c = (nch & 7) ^ (r & 7);   // source-side swizzle, linear LDS dest
      gld16(A  + (size_t)(m0 + r) * K + kb + c * 8, (char*)As + nch * 16);
      gld16(Bt + (size_t)(n0 + r) * K + kb + c * 8, (char*)Bs + nch * 16);
    }
    __syncthreads();
    frag8 aF[4][2], bF[4][2];
    #pragma unroll
    for (int i = 0; i < 4; ++i) {
      int ra = wm + i * 16 + lr;
      int rb = wn + i * 16 + lr;
      #pragma unroll
      for (int kk = 0; kk < 2; ++kk) {
        aF[i][kk] = *(const frag8*)((const char*)As + ra * 128 + (((lg + 4*kk) ^ (ra & 7)) << 4));
        bF[i][kk] = *(const frag8*)((const char*)Bs + rb * 128 + (((lg + 4*kk) ^ (rb & 7)) << 4));
      }
    }
    #pragma unroll
    for (int kk = 0; kk < 2; ++kk)
      #pragma unroll
      for (int i = 0; i < 4; ++i)
        #pragma unroll
        for (int j = 0; j < 4; ++j)
          acc[i][j] = MFMA(aF[i][kk], bF[j][kk], acc[i][j]);
    __syncthreads();
  }
  #pragma unroll
  for (int i = 0; i < 4; ++i) {
    int row = m0 + wm + i * 16 + lg * 4;
    #pragma unroll
    for (int j = 0; j < 4; ++j) {
      int col = n0 + wn + j * 16 + lr;
      #pragma unroll
      for (int rr = 0; rr < 4; ++rr) {
        if (OUT_BF16) ((unsigned short*)Cp)[(size_t)(row + rr) * N + col] = f2bf(acc[i][j][rr]);
        else          ((float*)Cp)[(size_t)(row + rr) * N + col] = acc[i][j][rr];
      }
    }
  }
}

// ---- RoPE applied in-place to q (cols 0..2047, scaled by 0.125) and k (2048..2559) ----
__global__ __launch_bounds__(256) void k_rope(unsigned short* __restrict__ qkv,
                                              const float* __restrict__ ct,
                                              const float* __restrict__ st){
  int idx = blockIdx.x * 256 + threadIdx.x;   // 4096 rows * 40 heads * 8 quads
  int p4 = idx & 7;
  int rest = idx >> 3;
  int hh = rest % 40;
  int row = rest / 40;
  int tpos = row & (Tn - 1);
  int colbase = (hh < 32) ? (hh << 6) : (2048 + ((hh - 32) << 6));
  int d0 = p4 << 2;
  unsigned short* base = qkv + (size_t)row * NQKV + colbase + d0;
  ushort4 av = *(const ushort4*)(base);
  ushort4 bv = *(const ushort4*)(base + 32);
  float4 c4 = *(const float4*)(ct + (tpos << 5) + d0);
  float4 s4 = *(const float4*)(st + (tpos << 5) + d0);
  float sc = (hh < 32) ? 0.125f : 1.0f;   // fold attention scale into q (exact pow2)
  float a0 = bf2f(av.x), a1 = bf2f(av.y), a2 = bf2f(av.z), a3 = bf2f(av.w);
  float b0 = bf2f(bv.x), b1 = bf2f(bv.y), b2 = bf2f(bv.z), b3 = bf2f(bv.w);
  ushort4 ra, rb;
  ra.x = f2bf((a0 * c4.x - b0 * s4.x) * sc);
  ra.y = f2bf((a1 * c4.y - b1 * s4.y) * sc);
  ra.z = f2bf((a2 * c4.z - b2 * s4.z) * sc);
  ra.w = f2bf((a3 * c4.w - b3 * s4.w) * sc);
  rb.x = f2bf((b0 * c4.x + a0 * s4.x) * sc);
  rb.y = f2bf((b1 * c4.y + a1 * s4.y) * sc);
  rb.z = f2bf((b2 * c4.z + a2 * s4.z) * sc);
  rb.w = f2bf((b3 * c4.w + a3 * s4.w) * sc);
  *(ushort4*)(base)      = ra;
  *(ushort4*)(base + 32) = rb;
}

// ---- V pre-transpose: vt[b*8+kvh][d][t] = v[b,t,kvh,d] ----
__global__ __launch_bounds__(256) void k_vt(const unsigned short* __restrict__ qkv,
                                            unsigned short* __restrict__ vt){
  __shared__ unsigned short tl[64][66];
  int head = blockIdx.y;
  int b = head >> 3, kvh = head & 7;
  int t0 = blockIdx.x * 64;
  int t = threadIdx.x;
  int r = t >> 2, cc = (t & 3) << 4;
  const unsigned short* p = qkv + (size_t)(b * Tn + t0 + r) * NQKV + 2560 + kvh * 64 + cc;
  U16x8 v0 = *(const U16x8*)(p);
  U16x8 v1 = *(const U16x8*)(p + 8);
  #pragma unroll
  for (int j = 0; j < 8; ++j) { tl[r][cc + j] = v0.s[j]; tl[r][cc + 8 + j] = v1.s[j]; }
  __syncthreads();
  int d = t >> 2, tc = (t & 3) << 4;
  U16x8 o0, o1;
  #pragma unroll
  for (int j = 0; j < 8; ++j) { o0.s[j] = tl[tc + j][d]; o1.s[j] = tl[tc + 8 + j][d]; }
  unsigned short* q = vt + ((size_t)head * 64 + d) * Tn + t0 + tc;
  *(U16x8*)(q) = o0; *(U16x8*)(q + 8) = o1;
}

// ---- flash attention: QBLK=64 (4 waves x 16 q-rows), KVBLK=64, swapped QK^T ----
__global__ __launch_bounds__(256) void k_attn(const unsigned short* __restrict__ qkv,
                                              const unsigned short* __restrict__ vt,
                                              unsigned short* __restrict__ y){
  __shared__ unsigned short Qs[64 * 64];
  __shared__ unsigned short Ks[64 * 64];
  __shared__ unsigned short Vs[64 * 64];        // Vt tile: [d][kv]
  __shared__ unsigned short Ps[4][16 * 64];     // per-wave P: [q][kv]
  int tid = threadIdx.x, w = tid >> 6, ln = tid & 63, lq = ln & 15, lg = ln >> 4;
  int bh = blockIdx.y, b = bh >> 5, h = bh & 31, kvh = h >> 2;
  int vhead = b * 8 + kvh;
  int q0 = blockIdx.x * 64;
  #pragma unroll
  for (int it = 0; it < 2; ++it) {
    int n = it * 256 + tid, r = n >> 3, c = (n & 7) ^ (r & 7);
    gld16(qkv + (size_t)(b * Tn + q0 + r) * NQKV + h * 64 + c * 8, (char*)Qs + n * 16);
  }
  __syncthreads();
  frag8 qF[2];
  {
    int row = w * 16 + lq;
    #pragma unroll
    for (int kk = 0; kk < 2; ++kk)
      qF[kk] = *(const frag8*)((const char*)Qs + row * 128 + (((lg + 4*kk) ^ (row & 7)) << 4));
  }
  fx4 o[4];
  #pragma unroll
  for (int i = 0; i < 4; ++i) o[i] = (fx4){0.f,0.f,0.f,0.f};
  float mrun = -1e30f, lrun = 0.f;
  char* pbase = (char*)&Ps[w][0];
  for (int kt = 0; kt < 32; ++kt) {
    int kv0 = kt << 6;
    #pragma unroll
    for (int it = 0; it < 2; ++it) {
      int n = it * 256 + tid, r = n >> 3, c = (n & 7) ^ (r & 7);
      gld16(qkv + (size_t)(b * Tn + kv0 + r) * NQKV + 2048 + kvh * 64 + c * 8, (char*)Ks + n * 16);
      gld16(vt + ((size_t)vhead * 64 + r) * Tn + kv0 + c * 8, (char*)Vs + n * 16);
    }
    __syncthreads();
    // S^T = K * Q^T  -> lane holds S^T[kv=16mf+4lg+rr][q=lq]
    fx4 sf[4];
    #pragma unroll
    for (int mf = 0; mf < 4; ++mf) {
      sf[mf] = (fx4){0.f,0.f,0.f,0.f};
      int row = mf * 16 + lq;
      #pragma unroll
      for (int kk = 0; kk < 2; ++kk) {
        frag8 kf = *(const frag8*)((const char*)Ks + row * 128 + (((lg + 4*kk) ^ (row & 7)) << 4));
        sf[mf] = MFMA(kf, qF[kk], sf[mf]);
      }
    }
    // online softmax over kv (16 regs in-lane + lanes lq, lq^16, lq^32, lq^48)
    float tmax = sf[0][0];
    #pragma unroll
    for (int mf = 0; mf < 4; ++mf)
      #pragma unroll
      for (int rr = 0; rr < 4; ++rr) tmax = fmaxf(tmax, sf[mf][rr]);
    tmax = fmaxf(tmax, __shfl_xor(tmax, 16));
    tmax = fmaxf(tmax, __shfl_xor(tmax, 32));
    float mnew = fmaxf(mrun, tmax);
    float fs = exp2f((mrun - mnew) * 1.44269504f);
    float psum = 0.f;
    #pragma unroll
    for (int mf = 0; mf < 4; ++mf) {
      float p0 = exp2f((sf[mf][0] - mnew) * 1.44269504f);
      float p1 = exp2f((sf[mf][1] - mnew) * 1.44269504f);
      float p2 = exp2f((sf[mf][2] - mnew) * 1.44269504f);
      float p3 = exp2f((sf[mf][3] - mnew) * 1.44269504f);
      psum += p0 + p1 + p2 + p3;
      unsigned lo = (unsigned)f2bf(p0) | ((unsigned)f2bf(p1) << 16);
      unsigned hi = (unsigned)f2bf(p2) | ((unsigned)f2bf(p3) << 16);
      *(uint2*)(pbase + lq * 128 + ((32 * mf + 8 * lg) ^ ((lq & 7) << 4))) = make_uint2(lo, hi);
    }
    psum += __shfl_xor(psum, 16);
    psum += __shfl_xor(psum, 32);
    lrun = lrun * fs + psum;
    mrun = mnew;
    #pragma unroll
    for (int i = 0; i < 4; ++i) o[i] *= fs;
    // O^T += Vt * P^T  (same-wave LDS write->read, no barrier needed)
    frag8 pF[2];
    #pragma unroll
    for (int kk = 0; kk < 2; ++kk)
      pF[kk] = *(const frag8*)((const char*)pbase + lq * 128 + (((lg + 4*kk) ^ (lq & 7)) << 4));
    #pragma unroll
    for (int df = 0; df < 4; ++df) {
      int row = df * 16 + lq;
      #pragma unroll
      for (int kk = 0; kk < 2; ++kk) {
        frag8 vf = *(const frag8*)((const char*)Vs + row * 128 + (((lg + 4*kk) ^ (row & 7)) << 4));
        o[df] = MFMA(vf, pF[kk], o[df]);
      }
    }
    __syncthreads();
  }
  float inv = 1.0f / lrun;
  unsigned short* yp = y + (size_t)(b * Tn + q0 + w * 16 + lq) * Cn + h * 64;
  #pragma unroll
  for (int df = 0; df < 4; ++df) {
    ushort4 pk;
    pk.x = f2bf(o[df][0] * inv); pk.y = f2bf(o[df][1] * inv);
    pk.z = f2bf(o[df][2] * inv); pk.w = f2bf(o[df][3] * inv);
    *(ushort4*)(yp + df * 16 + lg * 4) = pk;
  }
}

extern "C" void kernel_launch(void* const* d_in, const int* in_sizes, int n_in,
                              void* d_out, int out_size, void* d_ws, size_t ws_size,
                              hipStream_t stream){
  const float* x  = (const float*)d_in[0];
  const float* Wq = (const float*)d_in[1];
  const float* Wk = (const float*)d_in[2];
  const float* Wv = (const float*)d_in[3];
  const float* Wo = (const float*)d_in[4];
  char* ws = (char*)d_ws;
  size_t off = 0;
  unsigned short* xb    = (unsigned short*)(ws + off); off += (size_t)MR * KD * 2;     // 16.8 MB
  unsigned short* wqkvt = (unsigned short*)(ws + off); off += (size_t)NQKV * KD * 2;   // 12.6 MB
  unsigned short* wot   = (unsigned short*)(ws + off); off += (size_t)KD * KD * 2;     // 8.4 MB
  unsigned short* qkv   = (unsigned short*)(ws + off); off += (size_t)MR * NQKV * 2;   // 25.2 MB
  unsigned short* vtb   = (unsigned short*)(ws + off); off += (size_t)16 * 64 * Tn * 2;// 4.2 MB
  float* ctab = (float*)(ws + off); off += (size_t)Tn * 32 * 4;
  float* stab = (float*)(ws + off); off += (size_t)Tn * 32 * 4;
  unsigned short* yb = xb;  // xb is dead after GEMM1 -> reuse as attention output

  k_cvt<<<8192, 256, 0, stream>>>(x, xb);
  k_transW<<<dim3(48, 32), 256, 0, stream>>>(Wq, Wk, Wv, wqkvt);
  k_transW<<<dim3(32, 32), 256, 0, stream>>>(Wo, Wo, Wo, wot);
  k_ropetab<<<256, 256, 0, stream>>>(ctab, stab);
  k_gemm<1><<<dim3(NQKV / 128, MR / 128), 256, 0, stream>>>(xb, wqkvt, qkv, MR, NQKV, KD);
  k_rope<<<5120, 256, 0, stream>>>(qkv, ctab, stab);
  k_vt<<<dim3(Tn / 64, 16), 256, 0, stream>>>(qkv, vtb);
  k_attn<<<dim3(Tn / 64, 64), 256, 0, stream>>>(qkv, vtb, yb);
  k_gemm<0><<<dim3(KD / 128, MR / 128), 256, 0, stream>>>(yb, wot, d_out, MR, KD, KD);
}

// Round 2
// 296.890 us; speedup vs baseline: 1.0847x; 1.0847x over previous
//
#include <hip/hip_runtime.h>
#include <stdint.h>

// ---- problem constants ----
#define Tn   2048
#define Cn   2048
#define Hn   32
#define KVHn 8
#define Dn   64
#define MR   4096   // B*T
#define NQKV 3072   // 2048 q | 512 k | 512 v
#define KD   2048

typedef __attribute__((ext_vector_type(4))) float fx4;
typedef __attribute__((ext_vector_type(8))) short frag8;

#define MFMA(a,b,c) __builtin_amdgcn_mfma_f32_16x16x32_bf16((a),(b),(c),0,0,0)

struct __align__(16) U16x8 { unsigned short s[8]; };

__device__ __forceinline__ unsigned short f2bf(float x){
  union { float f; unsigned u; } v; v.f = x;
  return (unsigned short)((v.u + 0x7FFFu + ((v.u >> 16) & 1u)) >> 16);
}
__device__ __forceinline__ float bf2f(unsigned short h){
  union { unsigned u; float f; } v; v.u = ((unsigned)h) << 16; return v.f;
}

typedef const __attribute__((address_space(1))) void cas1_void;
typedef __attribute__((address_space(3))) void as3_void;
__device__ __forceinline__ void gld16(const void* g, void* l){
  __builtin_amdgcn_global_load_lds((cas1_void*)g, (as3_void*)l, 16, 0, 0);
}

// ---- fp32 -> bf16 convert (vectorized) ----
__global__ __launch_bounds__(256) void k_cvt(const float* __restrict__ in,
                                             unsigned short* __restrict__ out){
  size_t i = (size_t)blockIdx.x * 256 + threadIdx.x;
  float4 v = *(const float4*)(in + i * 4);
  ushort4 o; o.x = f2bf(v.x); o.y = f2bf(v.y); o.z = f2bf(v.z); o.w = f2bf(v.w);
  *(ushort4*)(out + i * 4) = o;
}

// ---- transpose + convert weights: out[n][k] (bf16) = W[k][n] (f32) ----
__global__ __launch_bounds__(256) void k_transW(const float* __restrict__ W0,
                                                const float* __restrict__ W1,
                                                const float* __restrict__ W2,
                                                unsigned short* __restrict__ out){
  __shared__ float tile[64][65];
  int n0 = blockIdx.x * 64, k0 = blockIdx.y * 64;
  const float* src; int col0, ld;
  if (n0 < 2048)      { src = W0; col0 = n0;        ld = 2048; }
  else if (n0 < 2560) { src = W1; col0 = n0 - 2048; ld = 512;  }
  else                { src = W2; col0 = n0 - 2560; ld = 512;  }
  int t = threadIdx.x;
  int r = t >> 2, cc = (t & 3) << 4;
  const float* p = src + (size_t)(k0 + r) * ld + col0 + cc;
  #pragma unroll
  for (int j = 0; j < 16; j += 4) {
    float4 v = *(const float4*)(p + j);
    tile[r][cc + j + 0] = v.x; tile[r][cc + j + 1] = v.y;
    tile[r][cc + j + 2] = v.z; tile[r][cc + j + 3] = v.w;
  }
  __syncthreads();
  int n = t >> 2, kc = (t & 3) << 4;
  unsigned short* q = out + (size_t)(n0 + n) * 2048 + k0 + kc;
  U16x8 o0, o1;
  #pragma unroll
  for (int j = 0; j < 8; ++j) o0.s[j] = f2bf(tile[kc + j][n]);
  #pragma unroll
  for (int j = 0; j < 8; ++j) o1.s[j] = f2bf(tile[kc + 8 + j][n]);
  *(U16x8*)(q) = o0;
  *(U16x8*)(q + 8) = o1;
}

// ---- RoPE cos/sin table: [2048][32] each ----
__global__ __launch_bounds__(256) void k_ropetab(float* __restrict__ ct, float* __restrict__ st){
  int i = blockIdx.x * 256 + threadIdx.x;
  int tp = i >> 5, d = i & 31;
  float inv = powf(10000.0f, -(float)d * (1.0f/32.0f));
  float fr = (float)tp * inv;
  ct[i] = cosf(fr); st[i] = sinf(fr);
}

// ---- m97-style GEMM: C[M][N] = A[M][K] * Bt[N][K]^T  (bf16 in, fp32 acc) ----
template<int OUT_BF16>
__global__ __launch_bounds__(256) void k_gemm(const unsigned short* __restrict__ A,
                                              const unsigned short* __restrict__ Bt,
                                              void* __restrict__ Cp,
                                              int M, int N, int K){
  __shared__ unsigned short As[128 * 64];
  __shared__ unsigned short Bs[128 * 64];
  int tid = threadIdx.x;
  int m0 = blockIdx.y * 128, n0 = blockIdx.x * 128;
  int w = tid >> 6, ln = tid & 63, lr = ln & 15, lg = ln >> 4;
  int wm = (w >> 1) * 64, wn = (w & 1) * 64;
  fx4 acc[4][4];
  #pragma unroll
  for (int i = 0; i < 4; ++i)
    #pragma unroll
    for (int j = 0; j < 4; ++j) acc[i][j] = (fx4){0.f,0.f,0.f,0.f};
  int steps = K >> 6;
  for (int kt = 0; kt < steps; ++kt) {
    int kb = kt << 6;
    #pragma unroll
    for (int it = 0; it < 4; ++it) {
      int nch = it * 256 + tid;
      int r = nch >> 3, c = (nch & 7) ^ (r & 7);   // source-side swizzle, linear LDS dest
      gld16(A  + (size_t)(m0 + r) * K + kb + c * 8, (char*)As + nch * 16);
      gld16(Bt + (size_t)(n0 + r) * K + kb + c * 8, (char*)Bs + nch * 16);
    }
    __syncthreads();
    frag8 aF[4][2], bF[4][2];
    #pragma unroll
    for (int i = 0; i < 4; ++i) {
      int ra = wm + i * 16 + lr;
      int rb = wn + i * 16 + lr;
      #pragma unroll
      for (int kk = 0; kk < 2; ++kk) {
        aF[i][kk] = *(const frag8*)((const char*)As + ra * 128 + (((lg + 4*kk) ^ (ra & 7)) << 4));
        bF[i][kk] = *(const frag8*)((const char*)Bs + rb * 128 + (((lg + 4*kk) ^ (rb & 7)) << 4));
      }
    }
    #pragma unroll
    for (int kk = 0; kk < 2; ++kk)
      #pragma unroll
      for (int i = 0; i < 4; ++i)
        #pragma unroll
        for (int j = 0; j < 4; ++j)
          acc[i][j] = MFMA(aF[i][kk], bF[j][kk], acc[i][j]);
    __syncthreads();
  }
  #pragma unroll
  for (int i = 0; i < 4; ++i) {
    int row = m0 + wm + i * 16 + lg * 4;
    #pragma unroll
    for (int j = 0; j < 4; ++j) {
      int col = n0 + wn + j * 16 + lr;
      #pragma unroll
      for (int rr = 0; rr < 4; ++rr) {
        if (OUT_BF16) ((unsigned short*)Cp)[(size_t)(row + rr) * N + col] = f2bf(acc[i][j][rr]);
        else          ((float*)Cp)[(size_t)(row + rr) * N + col] = acc[i][j][rr];
      }
    }
  }
}

// ---- RoPE in-place; q cols scaled by 0.125*log2(e) so attention softmax runs in exp2 domain ----
__global__ __launch_bounds__(256) void k_rope(unsigned short* __restrict__ qkv,
                                              const float* __restrict__ ct,
                                              const float* __restrict__ st){
  int idx = blockIdx.x * 256 + threadIdx.x;
  int p4 = idx & 7;
  int rest = idx >> 3;
  int hh = rest % 40;
  int row = rest / 40;
  int tpos = row & (Tn - 1);
  int colbase = (hh < 32) ? (hh << 6) : (2048 + ((hh - 32) << 6));
  int d0 = p4 << 2;
  unsigned short* base = qkv + (size_t)row * NQKV + colbase + d0;
  ushort4 av = *(const ushort4*)(base);
  ushort4 bv = *(const ushort4*)(base + 32);
  float4 c4 = *(const float4*)(ct + (tpos << 5) + d0);
  float4 s4 = *(const float4*)(st + (tpos << 5) + d0);
  float sc = (hh < 32) ? 0.180336880f : 1.0f;  // 0.125 * log2(e)
  float a0 = bf2f(av.x), a1 = bf2f(av.y), a2 = bf2f(av.z), a3 = bf2f(av.w);
  float b0 = bf2f(bv.x), b1 = bf2f(bv.y), b2 = bf2f(bv.z), b3 = bf2f(bv.w);
  ushort4 ra, rb;
  ra.x = f2bf((a0 * c4.x - b0 * s4.x) * sc);
  ra.y = f2bf((a1 * c4.y - b1 * s4.y) * sc);
  ra.z = f2bf((a2 * c4.z - b2 * s4.z) * sc);
  ra.w = f2bf((a3 * c4.w - b3 * s4.w) * sc);
  rb.x = f2bf((b0 * c4.x + a0 * s4.x) * sc);
  rb.y = f2bf((b1 * c4.y + a1 * s4.y) * sc);
  rb.z = f2bf((b2 * c4.z + a2 * s4.z) * sc);
  rb.w = f2bf((b3 * c4.w + a3 * s4.w) * sc);
  *(ushort4*)(base)      = ra;
  *(ushort4*)(base + 32) = rb;
}

// ---- V pre-transpose: vt[b*8+kvh][d][t] = v[b,t,kvh,d] ----
__global__ __launch_bounds__(256) void k_vt(const unsigned short* __restrict__ qkv,
                                            unsigned short* __restrict__ vt){
  __shared__ unsigned short tl[64][66];
  int head = blockIdx.y;
  int b = head >> 3, kvh = head & 7;
  int t0 = blockIdx.x * 64;
  int t = threadIdx.x;
  int r = t >> 2, cc = (t & 3) << 4;
  const unsigned short* p = qkv + (size_t)(b * Tn + t0 + r) * NQKV + 2560 + kvh * 64 + cc;
  U16x8 v0 = *(const U16x8*)(p);
  U16x8 v1 = *(const U16x8*)(p + 8);
  #pragma unroll
  for (int j = 0; j < 8; ++j) { tl[r][cc + j] = v0.s[j]; tl[r][cc + 8 + j] = v1.s[j]; }
  __syncthreads();
  int d = t >> 2, tc = (t & 3) << 4;
  U16x8 o0, o1;
  #pragma unroll
  for (int j = 0; j < 8; ++j) { o0.s[j] = tl[tc + j][d]; o1.s[j] = tl[tc + 8 + j][d]; }
  unsigned short* q = vt + ((size_t)head * 64 + d) * Tn + t0 + tc;
  *(U16x8*)(q) = o0; *(U16x8*)(q + 8) = o1;
}

// ---- flash attention: QBLK=64 (4 waves x 16 q-rows), KVBLK=64, swapped QK^T,
//      double-buffered K/V, defer-max, cvt_pk P packing, exp2-domain scores ----
__global__ __launch_bounds__(256) void k_attn(const unsigned short* __restrict__ qkv,
                                              const unsigned short* __restrict__ vt,
                                              unsigned short* __restrict__ y){
  __shared__ unsigned short Ks[2][64 * 64];
  __shared__ unsigned short Vs[2][64 * 64];     // Vt tile: [d][kv]
  __shared__ unsigned short Ps[4][16 * 64];     // per-wave P: [q][kv]
  int tid = threadIdx.x, w = tid >> 6, ln = tid & 63, lq = ln & 15, lg = ln >> 4;
  int bh = blockIdx.y, b = bh >> 5, h = bh & 31, kvh = h >> 2;
  int vhead = b * 8 + kvh;
  int q0 = blockIdx.x * 64;
  // Q fragments straight from global (one 16B load per lane per kk)
  frag8 qF[2];
  {
    const unsigned short* qrow = qkv + (size_t)(b * Tn + q0 + w * 16 + lq) * NQKV + h * 64;
    qF[0] = *(const frag8*)(qrow + lg * 8);
    qF[1] = *(const frag8*)(qrow + 32 + lg * 8);
  }
  const unsigned short* kg = qkv + (size_t)b * Tn * NQKV + 2048 + kvh * 64;
  const unsigned short* vg = vt + (size_t)vhead * 64 * Tn;

#define STAGE(KT, BUF)                                                              \
  {                                                                                 \
    int kv0_ = (KT) << 6;                                                           \
    _Pragma("unroll")                                                               \
    for (int it = 0; it < 2; ++it) {                                                \
      int n_ = it * 256 + tid, r_ = n_ >> 3, c_ = (n_ & 7) ^ (r_ & 7);              \
      gld16(kg + (size_t)(kv0_ + r_) * NQKV + c_ * 8, (char*)&Ks[BUF][0] + n_ * 16);\
      gld16(vg + (size_t)r_ * Tn + kv0_ + c_ * 8,     (char*)&Vs[BUF][0] + n_ * 16);\
    }                                                                               \
  }

  STAGE(0, 0);
  fx4 o[4];
  #pragma unroll
  for (int i = 0; i < 4; ++i) o[i] = (fx4){0.f,0.f,0.f,0.f};
  float mrun = -1e30f, lrun = 0.f;
  char* pbase = (char*)&Ps[w][0];
  __syncthreads();
  for (int kt = 0; kt < 32; ++kt) {
    int cur = kt & 1;
    if (kt < 31) STAGE(kt + 1, cur ^ 1);
    const char* kbase = (const char*)&Ks[cur][0];
    const char* vbase = (const char*)&Vs[cur][0];
    // S^T = K * Q^T  -> lane holds S^T[kv=16mf+4lg+rr][q=lq]   (exp2 domain)
    fx4 sf[4];
    #pragma unroll
    for (int mf = 0; mf < 4; ++mf) {
      sf[mf] = (fx4){0.f,0.f,0.f,0.f};
      int row = mf * 16 + lq;
      #pragma unroll
      for (int kk = 0; kk < 2; ++kk) {
        frag8 kf = *(const frag8*)(kbase + row * 128 + (((lg + 4*kk) ^ (row & 7)) << 4));
        sf[mf] = MFMA(kf, qF[kk], sf[mf]);
      }
    }
    // tile max (max3-friendly tree) + cross-lane
    float tmax;
    {
      float a0 = fmaxf(fmaxf(sf[0][0], sf[0][1]), fmaxf(sf[0][2], sf[0][3]));
      float a1 = fmaxf(fmaxf(sf[1][0], sf[1][1]), fmaxf(sf[1][2], sf[1][3]));
      float a2 = fmaxf(fmaxf(sf[2][0], sf[2][1]), fmaxf(sf[2][2], sf[2][3]));
      float a3 = fmaxf(fmaxf(sf[3][0], sf[3][1]), fmaxf(sf[3][2], sf[3][3]));
      tmax = fmaxf(fmaxf(a0, a1), fmaxf(a2, a3));
    }
    tmax = fmaxf(tmax, __shfl_xor(tmax, 16));
    tmax = fmaxf(tmax, __shfl_xor(tmax, 32));
    // defer-max: only rescale when the tile max meaningfully exceeds the running max
    if (__any(tmax > mrun + 8.0f)) {
      float mnew = fmaxf(mrun, tmax);
      float fs = exp2f(mrun - mnew);
      lrun *= fs;
      #pragma unroll
      for (int i = 0; i < 4; ++i) o[i] *= fs;
      mrun = mnew;
    }
    float psum = 0.f;
    #pragma unroll
    for (int mf = 0; mf < 4; ++mf) {
      float p0 = exp2f(sf[mf][0] - mrun);
      float p1 = exp2f(sf[mf][1] - mrun);
      float p2 = exp2f(sf[mf][2] - mrun);
      float p3 = exp2f(sf[mf][3] - mrun);
      psum += (p0 + p1) + (p2 + p3);
      unsigned lo, hi;
      asm("v_cvt_pk_bf16_f32 %0, %1, %2" : "=v"(lo) : "v"(p0), "v"(p1));
      asm("v_cvt_pk_bf16_f32 %0, %1, %2" : "=v"(hi) : "v"(p2), "v"(p3));
      *(uint2*)(pbase + lq * 128 + ((32 * mf + 8 * lg) ^ ((lq & 7) << 4))) = make_uint2(lo, hi);
    }
    psum += __shfl_xor(psum, 16);
    psum += __shfl_xor(psum, 32);
    lrun += psum;
    // O^T += Vt * P^T  (same-wave LDS write->read, no barrier needed)
    frag8 pF[2];
    #pragma unroll
    for (int kk = 0; kk < 2; ++kk)
      pF[kk] = *(const frag8*)((const char*)pbase + lq * 128 + (((lg + 4*kk) ^ (lq & 7)) << 4));
    #pragma unroll
    for (int df = 0; df < 4; ++df) {
      int row = df * 16 + lq;
      #pragma unroll
      for (int kk = 0; kk < 2; ++kk) {
        frag8 vf = *(const frag8*)(vbase + row * 128 + (((lg + 4*kk) ^ (row & 7)) << 4));
        o[df] = MFMA(vf, pF[kk], o[df]);
      }
    }
    __syncthreads();
  }
#undef STAGE
  float inv = 1.0f / lrun;
  unsigned short* yp = y + (size_t)(b * Tn + q0 + w * 16 + lq) * Cn + h * 64;
  #pragma unroll
  for (int df = 0; df < 4; ++df) {
    ushort4 pk;
    pk.x = f2bf(o[df][0] * inv); pk.y = f2bf(o[df][1] * inv);
    pk.z = f2bf(o[df][2] * inv); pk.w = f2bf(o[df][3] * inv);
    *(ushort4*)(yp + df * 16 + lg * 4) = pk;
  }
}

extern "C" void kernel_launch(void* const* d_in, const int* in_sizes, int n_in,
                              void* d_out, int out_size, void* d_ws, size_t ws_size,
                              hipStream_t stream){
  const float* x  = (const float*)d_in[0];
  const float* Wq = (const float*)d_in[1];
  const float* Wk = (const float*)d_in[2];
  const float* Wv = (const float*)d_in[3];
  const float* Wo = (const float*)d_in[4];
  char* ws = (char*)d_ws;
  size_t off = 0;
  unsigned short* xb    = (unsigned short*)(ws + off); off += (size_t)MR * KD * 2;
  unsigned short* wqkvt = (unsigned short*)(ws + off); off += (size_t)NQKV * KD * 2;
  unsigned short* wot   = (unsigned short*)(ws + off); off += (size_t)KD * KD * 2;
  unsigned short* qkv   = (unsigned short*)(ws + off); off += (size_t)MR * NQKV * 2;
  unsigned short* vtb   = (unsigned short*)(ws + off); off += (size_t)16 * 64 * Tn * 2;
  float* ctab = (float*)(ws + off); off += (size_t)Tn * 32 * 4;
  float* stab = (float*)(ws + off); off += (size_t)Tn * 32 * 4;
  unsigned short* yb = xb;  // xb dead after GEMM1 -> reuse as attention output

  k_cvt<<<8192, 256, 0, stream>>>(x, xb);
  k_transW<<<dim3(48, 32), 256, 0, stream>>>(Wq, Wk, Wv, wqkvt);
  k_transW<<<dim3(32, 32), 256, 0, stream>>>(Wo, Wo, Wo, wot);
  k_ropetab<<<256, 256, 0, stream>>>(ctab, stab);
  k_gemm<1><<<dim3(NQKV / 128, MR / 128), 256, 0, stream>>>(xb, wqkvt, qkv, MR, NQKV, KD);
  k_rope<<<5120, 256, 0, stream>>>(qkv, ctab, stab);
  k_vt<<<dim3(Tn / 64, 16), 256, 0, stream>>>(qkv, vtb);
  k_attn<<<dim3(Tn / 64, 64), 256, 0, stream>>>(qkv, vtb, yb);
  k_gemm<0><<<dim3(KD / 128, MR / 128), 256, 0, stream>>>(yb, wot, d_out, MR, KD, KD);
}

// Round 4
// 238.003 us; speedup vs baseline: 1.3530x; 1.2474x over previous
//
#include <hip/hip_runtime.h>
#include <stdint.h>

// ---- problem constants ----
#define Tn   2048
#define Cn   2048
#define Hn   32
#define KVHn 8
#define Dn   64
#define MR   4096   // B*T
#define NQKV 3072   // 2048 q | 512 k | 512 v
#define KD   2048

typedef __attribute__((ext_vector_type(4))) float fx4;
typedef __attribute__((ext_vector_type(8))) short frag8;

#define MFMA(a,b,c) __builtin_amdgcn_mfma_f32_16x16x32_bf16((a),(b),(c),0,0,0)

struct __align__(16) U16x8 { unsigned short s[8]; };

__device__ __forceinline__ unsigned short f2bf(float x){
  union { float f; unsigned u; } v; v.f = x;
  return (unsigned short)((v.u + 0x7FFFu + ((v.u >> 16) & 1u)) >> 16);
}
__device__ __forceinline__ float bf2f(unsigned short h){
  union { unsigned u; float f; } v; v.u = ((unsigned)h) << 16; return v.f;
}
// exp2 via compiler-known intrinsic (hazard-safe), clamped upstream by caller
__device__ __forceinline__ float sexp2(float x){
#if __has_builtin(__builtin_amdgcn_exp2f)
  return __builtin_amdgcn_exp2f(x);
#else
  return exp2f(x);
#endif
}
__device__ __forceinline__ unsigned cvtpk(float a, float b){
  unsigned r; asm("v_cvt_pk_bf16_f32 %0, %1, %2" : "=v"(r) : "v"(a), "v"(b)); return r;
}

typedef const __attribute__((address_space(1))) void cas1_void;
typedef __attribute__((address_space(3))) void as3_void;
__device__ __forceinline__ void gld16(const void* g, void* l){
  __builtin_amdgcn_global_load_lds((cas1_void*)g, (as3_void*)l, 16, 0, 0);
}

// ---- fp32 -> bf16 convert (vectorized) ----
__global__ __launch_bounds__(256) void k_cvt(const float* __restrict__ in,
                                             unsigned short* __restrict__ out){
  size_t i = (size_t)blockIdx.x * 256 + threadIdx.x;
  float4 v = *(const float4*)(in + i * 4);
  ushort4 o; o.x = f2bf(v.x); o.y = f2bf(v.y); o.z = f2bf(v.z); o.w = f2bf(v.w);
  *(ushort4*)(out + i * 4) = o;
}

// ---- transpose + convert weights: out[n][k] (bf16) = W[k][n] (f32) ----
__global__ __launch_bounds__(256) void k_transW(const float* __restrict__ W0,
                                                const float* __restrict__ W1,
                                                const float* __restrict__ W2,
                                                unsigned short* __restrict__ out){
  __shared__ float tile[64][65];
  int n0 = blockIdx.x * 64, k0 = blockIdx.y * 64;
  const float* src; int col0, ld;
  if (n0 < 2048)      { src = W0; col0 = n0;        ld = 2048; }
  else if (n0 < 2560) { src = W1; col0 = n0 - 2048; ld = 512;  }
  else                { src = W2; col0 = n0 - 2560; ld = 512;  }
  int t = threadIdx.x;
  int r = t >> 2, cc = (t & 3) << 4;
  const float* p = src + (size_t)(k0 + r) * ld + col0 + cc;
  #pragma unroll
  for (int j = 0; j < 16; j += 4) {
    float4 v = *(const float4*)(p + j);
    tile[r][cc + j + 0] = v.x; tile[r][cc + j + 1] = v.y;
    tile[r][cc + j + 2] = v.z; tile[r][cc + j + 3] = v.w;
  }
  __syncthreads();
  int n = t >> 2, kc = (t & 3) << 4;
  unsigned short* q = out + (size_t)(n0 + n) * 2048 + k0 + kc;
  U16x8 o0, o1;
  #pragma unroll
  for (int j = 0; j < 8; ++j) o0.s[j] = f2bf(tile[kc + j][n]);
  #pragma unroll
  for (int j = 0; j < 8; ++j) o1.s[j] = f2bf(tile[kc + 8 + j][n]);
  *(U16x8*)(q) = o0;
  *(U16x8*)(q + 8) = o1;
}

// ---- RoPE cos/sin table: [2048][32] each ----
__global__ __launch_bounds__(256) void k_ropetab(float* __restrict__ ct, float* __restrict__ st){
  int i = blockIdx.x * 256 + threadIdx.x;
  int tp = i >> 5, d = i & 31;
  float inv = powf(10000.0f, -(float)d * (1.0f/32.0f));
  float fr = (float)tp * inv;
  ct[i] = cosf(fr); st[i] = sinf(fr);
}

// ---- m97-style GEMM: C[M][N] = A[M][K] * Bt[N][K]^T  (bf16 in, fp32 acc) ----
template<int OUT_BF16>
__global__ __launch_bounds__(256) void k_gemm(const unsigned short* __restrict__ A,
                                              const unsigned short* __restrict__ Bt,
                                              void* __restrict__ Cp,
                                              int M, int N, int K){
  __shared__ unsigned short As[128 * 64];
  __shared__ unsigned short Bs[128 * 64];
  int tid = threadIdx.x;
  int m0 = blockIdx.y * 128, n0 = blockIdx.x * 128;
  int w = tid >> 6, ln = tid & 63, lr = ln & 15, lg = ln >> 4;
  int wm = (w >> 1) * 64, wn = (w & 1) * 64;
  fx4 acc[4][4];
  #pragma unroll
  for (int i = 0; i < 4; ++i)
    #pragma unroll
    for (int j = 0; j < 4; ++j) acc[i][j] = (fx4){0.f,0.f,0.f,0.f};
  int steps = K >> 6;
  for (int kt = 0; kt < steps; ++kt) {
    int kb = kt << 6;
    #pragma unroll
    for (int it = 0; it < 4; ++it) {
      int nch = it * 256 + tid;
      int r = nch >> 3, c = (nch & 7) ^ (r & 7);   // source-side swizzle, linear LDS dest
      gld16(A  + (size_t)(m0 + r) * K + kb + c * 8, (char*)As + nch * 16);
      gld16(Bt + (size_t)(n0 + r) * K + kb + c * 8, (char*)Bs + nch * 16);
    }
    __syncthreads();
    frag8 aF[4][2], bF[4][2];
    #pragma unroll
    for (int i = 0; i < 4; ++i) {
      int ra = wm + i * 16 + lr;
      int rb = wn + i * 16 + lr;
      #pragma unroll
      for (int kk = 0; kk < 2; ++kk) {
        aF[i][kk] = *(const frag8*)((const char*)As + ra * 128 + (((lg + 4*kk) ^ (ra & 7)) << 4));
        bF[i][kk] = *(const frag8*)((const char*)Bs + rb * 128 + (((lg + 4*kk) ^ (rb & 7)) << 4));
      }
    }
    #pragma unroll
    for (int kk = 0; kk < 2; ++kk)
      #pragma unroll
      for (int i = 0; i < 4; ++i)
        #pragma unroll
        for (int j = 0; j < 4; ++j)
          acc[i][j] = MFMA(aF[i][kk], bF[j][kk], acc[i][j]);
    __syncthreads();
  }
  #pragma unroll
  for (int i = 0; i < 4; ++i) {
    int row = m0 + wm + i * 16 + lg * 4;
    #pragma unroll
    for (int j = 0; j < 4; ++j) {
      int col = n0 + wn + j * 16 + lr;
      #pragma unroll
      for (int rr = 0; rr < 4; ++rr) {
        if (OUT_BF16) ((unsigned short*)Cp)[(size_t)(row + rr) * N + col] = f2bf(acc[i][j][rr]);
        else          ((float*)Cp)[(size_t)(row + rr) * N + col] = acc[i][j][rr];
      }
    }
  }
}

// ---- RoPE in-place; q cols scaled by 0.125*log2(e) so attention softmax runs in exp2 domain ----
__global__ __launch_bounds__(256) void k_rope(unsigned short* __restrict__ qkv,
                                              const float* __restrict__ ct,
                                              const float* __restrict__ st){
  int idx = blockIdx.x * 256 + threadIdx.x;
  int p4 = idx & 7;
  int rest = idx >> 3;
  int hh = rest % 40;
  int row = rest / 40;
  int tpos = row & (Tn - 1);
  int colbase = (hh < 32) ? (hh << 6) : (2048 + ((hh - 32) << 6));
  int d0 = p4 << 2;
  unsigned short* base = qkv + (size_t)row * NQKV + colbase + d0;
  ushort4 av = *(const ushort4*)(base);
  ushort4 bv = *(const ushort4*)(base + 32);
  float4 c4 = *(const float4*)(ct + (tpos << 5) + d0);
  float4 s4 = *(const float4*)(st + (tpos << 5) + d0);
  float sc = (hh < 32) ? 0.180336880f : 1.0f;  // 0.125 * log2(e)
  float a0 = bf2f(av.x), a1 = bf2f(av.y), a2 = bf2f(av.z), a3 = bf2f(av.w);
  float b0 = bf2f(bv.x), b1 = bf2f(bv.y), b2 = bf2f(bv.z), b3 = bf2f(bv.w);
  ushort4 ra, rb;
  ra.x = f2bf((a0 * c4.x - b0 * s4.x) * sc);
  ra.y = f2bf((a1 * c4.y - b1 * s4.y) * sc);
  ra.z = f2bf((a2 * c4.z - b2 * s4.z) * sc);
  ra.w = f2bf((a3 * c4.w - b3 * s4.w) * sc);
  rb.x = f2bf((b0 * c4.x + a0 * s4.x) * sc);
  rb.y = f2bf((b1 * c4.y + a1 * s4.y) * sc);
  rb.z = f2bf((b2 * c4.z + a2 * s4.z) * sc);
  rb.w = f2bf((b3 * c4.w + a3 * s4.w) * sc);
  *(ushort4*)(base)      = ra;
  *(ushort4*)(base + 32) = rb;
}

// ---- V pre-transpose WITH quad-interleave: within each 64-t block, 16B chunk c
//      of row d holds t-offsets 32*(c>>2) + 16*(e>>2) + 4*(c&3) + (e&3), matching
//      the P registers produced by swapped-QK^T (slot-consistent contraction). ----
__global__ __launch_bounds__(256) void k_vt(const unsigned short* __restrict__ qkv,
                                            unsigned short* __restrict__ vt){
  __shared__ unsigned short tl[64][66];   // [t][d]
  int head = blockIdx.y;
  int b = head >> 3, kvh = head & 7;
  int t0 = blockIdx.x * 64;
  int t = threadIdx.x;
  int r = t >> 2, cc = (t & 3) << 4;
  const unsigned short* p = qkv + (size_t)(b * Tn + t0 + r) * NQKV + 2560 + kvh * 64 + cc;
  U16x8 v0 = *(const U16x8*)(p);
  U16x8 v1 = *(const U16x8*)(p + 8);
  #pragma unroll
  for (int j = 0; j < 8; ++j) { tl[r][cc + j] = v0.s[j]; tl[r][cc + 8 + j] = v1.s[j]; }
  __syncthreads();
  int d = t >> 2, cpair = t & 3;
  unsigned short* q = vt + ((size_t)head * 64 + d) * Tn + t0;
  #pragma unroll
  for (int ci = 0; ci < 2; ++ci) {
    int c = cpair * 2 + ci;
    U16x8 oo;
    #pragma unroll
    for (int e = 0; e < 8; ++e)
      oo.s[e] = tl[32 * (c >> 2) + 16 * (e >> 2) + 4 * (c & 3) + (e & 3)][d];
    *(U16x8*)(q + c * 8) = oo;
  }
}

// ---- flash attention: QBLK=128 (4 waves x 32 q-rows), KVBLK=64, swapped QK^T,
//      fixed softmax origin (m=0, exp2 domain, clamped), P held in registers
//      (permuted contraction), double-buffered K/V via global_load_lds ----
__global__ __launch_bounds__(256) void k_attn(const unsigned short* __restrict__ qkv,
                                              const unsigned short* __restrict__ vt,
                                              unsigned short* __restrict__ y){
  __shared__ unsigned short Ks[2][64 * 64];
  __shared__ unsigned short Vs[2][64 * 64];   // quad-interleaved Vt tile: [d][kv-perm]
  int tid = threadIdx.x, w = tid >> 6, ln = tid & 63, lq = ln & 15, lg = ln >> 4;
  int bh = blockIdx.y, b = bh >> 5, h = bh & 31, kvh = h >> 2;
  int q0 = blockIdx.x * 128;
  // Q fragments straight from global
  frag8 qF[2][2];
  #pragma unroll
  for (int s = 0; s < 2; ++s) {
    const unsigned short* qrow = qkv + (size_t)(b * Tn + q0 + w * 32 + 16 * s + lq) * NQKV + h * 64;
    qF[s][0] = *(const frag8*)(qrow + lg * 8);
    qF[s][1] = *(const frag8*)(qrow + 32 + lg * 8);
  }
  // per-lane staging pointers (source-side chunk swizzle, linear LDS dest)
  int n0 = tid, n1 = 256 + tid;
  int r0 = n0 >> 3, c0 = (n0 & 7) ^ (r0 & 7);
  int r1 = n1 >> 3, c1 = (n1 & 7) ^ (r1 & 7);
  const unsigned short* kp0 = qkv + (size_t)b * Tn * NQKV + 2048 + kvh * 64 + (size_t)r0 * NQKV + c0 * 8;
  const unsigned short* kp1 = qkv + (size_t)b * Tn * NQKV + 2048 + kvh * 64 + (size_t)r1 * NQKV + c1 * 8;
  const unsigned short* vp0 = vt + ((size_t)(b * 8 + kvh) * 64 + r0) * Tn + c0 * 8;
  const unsigned short* vp1 = vt + ((size_t)(b * 8 + kvh) * 64 + r1) * Tn + c1 * 8;
  // per-lane LDS fragment byte offsets (kt-invariant; row&7 == lq&7)
  int koff0 = lq * 128 + (((lg)     ^ (lq & 7)) << 4);
  int koff1 = lq * 128 + (((lg + 4) ^ (lq & 7)) << 4);

#define STAGE(BUF) do {                                      \
    gld16(kp0, (char*)&Ks[BUF][0] + n0 * 16);                \
    gld16(kp1, (char*)&Ks[BUF][0] + n1 * 16);                \
    gld16(vp0, (char*)&Vs[BUF][0] + n0 * 16);                \
    gld16(vp1, (char*)&Vs[BUF][0] + n1 * 16);                \
    kp0 += 64 * NQKV; kp1 += 64 * NQKV; vp0 += 64; vp1 += 64;\
  } while (0)

#define PB(S, KK) ({ union { unsigned u[4]; frag8 f; } t_;                        \
    t_.u[0] = pu[S][2*(KK)][0]; t_.u[1] = pu[S][2*(KK)][1];                       \
    t_.u[2] = pu[S][2*(KK)+1][0]; t_.u[3] = pu[S][2*(KK)+1][1]; t_.f; })

#define COMPUTE(BUF) do {                                                         \
    const char* kb_ = (const char*)&Ks[BUF][0];                                   \
    const char* vb_ = (const char*)&Vs[BUF][0];                                   \
    frag8 kf[4][2];                                                               \
    _Pragma("unroll")                                                             \
    for (int mf = 0; mf < 4; ++mf) {                                              \
      kf[mf][0] = *(const frag8*)(kb_ + mf * 2048 + koff0);                       \
      kf[mf][1] = *(const frag8*)(kb_ + mf * 2048 + koff1);                       \
    }                                                                             \
    fx4 sf[2][4];                                                                 \
    _Pragma("unroll")                                                             \
    for (int s = 0; s < 2; ++s)                                                   \
      _Pragma("unroll")                                                           \
      for (int mf = 0; mf < 4; ++mf) {                                            \
        sf[s][mf] = (fx4){0.f, 0.f, 0.f, 0.f};                                    \
        sf[s][mf] = MFMA(kf[mf][0], qF[s][0], sf[s][mf]);                         \
        sf[s][mf] = MFMA(kf[mf][1], qF[s][1], sf[s][mf]);                         \
      }                                                                           \
    unsigned pu[2][4][2];                                                         \
    _Pragma("unroll")                                                             \
    for (int s = 0; s < 2; ++s) {                                                 \
      float ps = 0.f;                                                             \
      _Pragma("unroll")                                                           \
      for (int mf = 0; mf < 4; ++mf) {                                            \
        float p0 = sexp2(fminf(sf[s][mf][0], 63.f));                              \
        float p1 = sexp2(fminf(sf[s][mf][1], 63.f));                              \
        float p2 = sexp2(fminf(sf[s][mf][2], 63.f));                              \
        float p3 = sexp2(fminf(sf[s][mf][3], 63.f));                              \
        ps += (p0 + p1) + (p2 + p3);                                              \
        pu[s][mf][0] = cvtpk(p0, p1);                                             \
        pu[s][mf][1] = cvtpk(p2, p3);                                             \
      }                                                                           \
      ps += __shfl_xor(ps, 16);                                                   \
      ps += __shfl_xor(ps, 32);                                                   \
      l[s] += ps;                                                                 \
    }                                                                             \
    frag8 vf[4][2];                                                               \
    _Pragma("unroll")                                                             \
    for (int df = 0; df < 4; ++df) {                                              \
      vf[df][0] = *(const frag8*)(vb_ + df * 2048 + koff0);                       \
      vf[df][1] = *(const frag8*)(vb_ + df * 2048 + koff1);                       \
    }                                                                             \
    _Pragma("unroll")                                                             \
    for (int s = 0; s < 2; ++s)                                                   \
      _Pragma("unroll")                                                           \
      for (int df = 0; df < 4; ++df) {                                            \
        o[s][df] = MFMA(vf[df][0], PB(s, 0), o[s][df]);                           \
        o[s][df] = MFMA(vf[df][1], PB(s, 1), o[s][df]);                           \
      }                                                                           \
  } while (0)

  fx4 o[2][4];
  #pragma unroll
  for (int s = 0; s < 2; ++s)
    #pragma unroll
    for (int i = 0; i < 4; ++i) o[s][i] = (fx4){0.f, 0.f, 0.f, 0.f};
  float l[2] = {0.f, 0.f};

  STAGE(0);                 // tile 0 -> buf0
  __syncthreads();          // drain stage(0)
  for (int kt = 0; kt < 32; kt += 2) {
    STAGE(1);               // tile kt+1 -> buf1
    COMPUTE(0);             // tile kt
    __syncthreads();
    if (kt + 2 < 32) STAGE(0);   // tile kt+2 -> buf0
    COMPUTE(1);             // tile kt+1
    __syncthreads();
  }
#undef STAGE
#undef COMPUTE
#undef PB

  #pragma unroll
  for (int s = 0; s < 2; ++s) {
    float inv = 1.0f / l[s];
    unsigned short* yp = y + (size_t)(b * Tn + q0 + w * 32 + 16 * s + lq) * Cn + h * 64;
    #pragma unroll
    for (int df = 0; df < 4; ++df) {
      unsigned lo = cvtpk(o[s][df][0] * inv, o[s][df][1] * inv);
      unsigned hi = cvtpk(o[s][df][2] * inv, o[s][df][3] * inv);
      *(uint2*)(yp + df * 16 + lg * 4) = make_uint2(lo, hi);
    }
  }
}

extern "C" void kernel_launch(void* const* d_in, const int* in_sizes, int n_in,
                              void* d_out, int out_size, void* d_ws, size_t ws_size,
                              hipStream_t stream){
  const float* x  = (const float*)d_in[0];
  const float* Wq = (const float*)d_in[1];
  const float* Wk = (const float*)d_in[2];
  const float* Wv = (const float*)d_in[3];
  const float* Wo = (const float*)d_in[4];
  char* ws = (char*)d_ws;
  size_t off = 0;
  unsigned short* xb    = (unsigned short*)(ws + off); off += (size_t)MR * KD * 2;
  unsigned short* wqkvt = (unsigned short*)(ws + off); off += (size_t)NQKV * KD * 2;
  unsigned short* wot   = (unsigned short*)(ws + off); off += (size_t)KD * KD * 2;
  unsigned short* qkv   = (unsigned short*)(ws + off); off += (size_t)MR * NQKV * 2;
  unsigned short* vtb   = (unsigned short*)(ws + off); off += (size_t)16 * 64 * Tn * 2;
  float* ctab = (float*)(ws + off); off += (size_t)Tn * 32 * 4;
  float* stab = (float*)(ws + off); off += (size_t)Tn * 32 * 4;
  unsigned short* yb = xb;  // xb dead after GEMM1 -> reuse as attention output

  k_cvt<<<8192, 256, 0, stream>>>(x, xb);
  k_transW<<<dim3(48, 32), 256, 0, stream>>>(Wq, Wk, Wv, wqkvt);
  k_transW<<<dim3(32, 32), 256, 0, stream>>>(Wo, Wo, Wo, wot);
  k_ropetab<<<256, 256, 0, stream>>>(ctab, stab);
  k_gemm<1><<<dim3(NQKV / 128, MR / 128), 256, 0, stream>>>(xb, wqkvt, qkv, MR, NQKV, KD);
  k_rope<<<5120, 256, 0, stream>>>(qkv, ctab, stab);
  k_vt<<<dim3(Tn / 64, 16), 256, 0, stream>>>(qkv, vtb);
  k_attn<<<dim3(Tn / 128, 64), 256, 0, stream>>>(qkv, vtb, yb);
  k_gemm<0><<<dim3(KD / 128, MR / 128), 256, 0, stream>>>(yb, wot, d_out, MR, KD, KD);
}

// Round 6
// 227.824 us; speedup vs baseline: 1.4135x; 1.0447x over previous
//
#include <hip/hip_runtime.h>
#include <stdint.h>

// ---- problem constants ----
#define Tn   2048
#define Cn   2048
#define Hn   32
#define KVHn 8
#define Dn   64
#define MR   4096   // B*T
#define NQKV 3072   // 2048 q | 512 k | 512 v
#define KD   2048

typedef __attribute__((ext_vector_type(4))) float fx4;
typedef __attribute__((ext_vector_type(8))) short frag8;

#define MFMA(a,b,c) __builtin_amdgcn_mfma_f32_16x16x32_bf16((a),(b),(c),0,0,0)

struct __align__(16) U16x8 { unsigned short s[8]; };

__device__ __forceinline__ unsigned short f2bf(float x){
  union { float f; unsigned u; } v; v.f = x;
  return (unsigned short)((v.u + 0x7FFFu + ((v.u >> 16) & 1u)) >> 16);
}
__device__ __forceinline__ float bf2f(unsigned short h){
  union { unsigned u; float f; } v; v.u = ((unsigned)h) << 16; return v.f;
}
// exp2 via compiler-known intrinsic (hazard-safe)
__device__ __forceinline__ float sexp2(float x){
#if __has_builtin(__builtin_amdgcn_exp2f)
  return __builtin_amdgcn_exp2f(x);
#else
  return exp2f(x);
#endif
}
__device__ __forceinline__ unsigned cvtpk(float a, float b){
  unsigned r; asm("v_cvt_pk_bf16_f32 %0, %1, %2" : "=v"(r) : "v"(a), "v"(b)); return r;
}

typedef const __attribute__((address_space(1))) void cas1_void;
typedef __attribute__((address_space(3))) void as3_void;
__device__ __forceinline__ void gld16(const void* g, void* l){
  __builtin_amdgcn_global_load_lds((cas1_void*)g, (as3_void*)l, 16, 0, 0);
}

// ---- fp32 -> bf16 convert (vectorized) ----
__global__ __launch_bounds__(256) void k_cvt(const float* __restrict__ in,
                                             unsigned short* __restrict__ out){
  size_t i = (size_t)blockIdx.x * 256 + threadIdx.x;
  float4 v = *(const float4*)(in + i * 4);
  ushort4 o; o.x = f2bf(v.x); o.y = f2bf(v.y); o.z = f2bf(v.z); o.w = f2bf(v.w);
  *(ushort4*)(out + i * 4) = o;
}

// ---- transpose + convert weights: out[n][k] (bf16) = W[k][n] (f32) ----
__global__ __launch_bounds__(256) void k_transW(const float* __restrict__ W0,
                                                const float* __restrict__ W1,
                                                const float* __restrict__ W2,
                                                unsigned short* __restrict__ out){
  __shared__ float tile[64][65];
  int n0 = blockIdx.x * 64, k0 = blockIdx.y * 64;
  const float* src; int col0, ld;
  if (n0 < 2048)      { src = W0; col0 = n0;        ld = 2048; }
  else if (n0 < 2560) { src = W1; col0 = n0 - 2048; ld = 512;  }
  else                { src = W2; col0 = n0 - 2560; ld = 512;  }
  int t = threadIdx.x;
  int r = t >> 2, cc = (t & 3) << 4;
  const float* p = src + (size_t)(k0 + r) * ld + col0 + cc;
  #pragma unroll
  for (int j = 0; j < 16; j += 4) {
    float4 v = *(const float4*)(p + j);
    tile[r][cc + j + 0] = v.x; tile[r][cc + j + 1] = v.y;
    tile[r][cc + j + 2] = v.z; tile[r][cc + j + 3] = v.w;
  }
  __syncthreads();
  int n = t >> 2, kc = (t & 3) << 4;
  unsigned short* q = out + (size_t)(n0 + n) * 2048 + k0 + kc;
  U16x8 o0, o1;
  #pragma unroll
  for (int j = 0; j < 8; ++j) o0.s[j] = f2bf(tile[kc + j][n]);
  #pragma unroll
  for (int j = 0; j < 8; ++j) o1.s[j] = f2bf(tile[kc + 8 + j][n]);
  *(U16x8*)(q) = o0;
  *(U16x8*)(q + 8) = o1;
}

// ---- RoPE cos/sin table: [2048][32] each ----
__global__ __launch_bounds__(256) void k_ropetab(float* __restrict__ ct, float* __restrict__ st){
  int i = blockIdx.x * 256 + threadIdx.x;
  int tp = i >> 5, d = i & 31;
  float inv = powf(10000.0f, -(float)d * (1.0f/32.0f));
  float fr = (float)tp * inv;
  ct[i] = cosf(fr); st[i] = sinf(fr);
}

// ---- m97-style GEMM: C[M][N] = A[M][K] * Bt[N][K]^T  (bf16 in, fp32 acc) ----
template<int OUT_BF16>
__global__ __launch_bounds__(256) void k_gemm(const unsigned short* __restrict__ A,
                                              const unsigned short* __restrict__ Bt,
                                              void* __restrict__ Cp,
                                              int M, int N, int K){
  __shared__ unsigned short As[128 * 64];
  __shared__ unsigned short Bs[128 * 64];
  int tid = threadIdx.x;
  int m0 = blockIdx.y * 128, n0 = blockIdx.x * 128;
  int w = tid >> 6, ln = tid & 63, lr = ln & 15, lg = ln >> 4;
  int wm = (w >> 1) * 64, wn = (w & 1) * 64;
  fx4 acc[4][4];
  #pragma unroll
  for (int i = 0; i < 4; ++i)
    #pragma unroll
    for (int j = 0; j < 4; ++j) acc[i][j] = (fx4){0.f,0.f,0.f,0.f};
  int steps = K >> 6;
  for (int kt = 0; kt < steps; ++kt) {
    int kb = kt << 6;
    #pragma unroll
    for (int it = 0; it < 4; ++it) {
      int nch = it * 256 + tid;
      int r = nch >> 3, c = (nch & 7) ^ (r & 7);   // source-side swizzle, linear LDS dest
      gld16(A  + (size_t)(m0 + r) * K + kb + c * 8, (char*)As + nch * 16);
      gld16(Bt + (size_t)(n0 + r) * K + kb + c * 8, (char*)Bs + nch * 16);
    }
    __syncthreads();
    frag8 aF[4][2], bF[4][2];
    #pragma unroll
    for (int i = 0; i < 4; ++i) {
      int ra = wm + i * 16 + lr;
      int rb = wn + i * 16 + lr;
      #pragma unroll
      for (int kk = 0; kk < 2; ++kk) {
        aF[i][kk] = *(const frag8*)((const char*)As + ra * 128 + (((lg + 4*kk) ^ (ra & 7)) << 4));
        bF[i][kk] = *(const frag8*)((const char*)Bs + rb * 128 + (((lg + 4*kk) ^ (rb & 7)) << 4));
      }
    }
    #pragma unroll
    for (int kk = 0; kk < 2; ++kk)
      #pragma unroll
      for (int i = 0; i < 4; ++i)
        #pragma unroll
        for (int j = 0; j < 4; ++j)
          acc[i][j] = MFMA(aF[i][kk], bF[j][kk], acc[i][j]);
    __syncthreads();
  }
  #pragma unroll
  for (int i = 0; i < 4; ++i) {
    int row = m0 + wm + i * 16 + lg * 4;
    #pragma unroll
    for (int j = 0; j < 4; ++j) {
      int col = n0 + wn + j * 16 + lr;
      #pragma unroll
      for (int rr = 0; rr < 4; ++rr) {
        if (OUT_BF16) ((unsigned short*)Cp)[(size_t)(row + rr) * N + col] = f2bf(acc[i][j][rr]);
        else          ((float*)Cp)[(size_t)(row + rr) * N + col] = acc[i][j][rr];
      }
    }
  }
}

// ---- RoPE in-place; q cols scaled by 0.125*log2(e) so attention softmax runs in exp2 domain ----
__global__ __launch_bounds__(256) void k_rope(unsigned short* __restrict__ qkv,
                                              const float* __restrict__ ct,
                                              const float* __restrict__ st){
  int idx = blockIdx.x * 256 + threadIdx.x;
  int p4 = idx & 7;
  int rest = idx >> 3;
  int hh = rest % 40;
  int row = rest / 40;
  int tpos = row & (Tn - 1);
  int colbase = (hh < 32) ? (hh << 6) : (2048 + ((hh - 32) << 6));
  int d0 = p4 << 2;
  unsigned short* base = qkv + (size_t)row * NQKV + colbase + d0;
  ushort4 av = *(const ushort4*)(base);
  ushort4 bv = *(const ushort4*)(base + 32);
  float4 c4 = *(const float4*)(ct + (tpos << 5) + d0);
  float4 s4 = *(const float4*)(st + (tpos << 5) + d0);
  float sc = (hh < 32) ? 0.180336880f : 1.0f;  // 0.125 * log2(e)
  float a0 = bf2f(av.x), a1 = bf2f(av.y), a2 = bf2f(av.z), a3 = bf2f(av.w);
  float b0 = bf2f(bv.x), b1 = bf2f(bv.y), b2 = bf2f(bv.z), b3 = bf2f(bv.w);
  ushort4 ra, rb;
  ra.x = f2bf((a0 * c4.x - b0 * s4.x) * sc);
  ra.y = f2bf((a1 * c4.y - b1 * s4.y) * sc);
  ra.z = f2bf((a2 * c4.z - b2 * s4.z) * sc);
  ra.w = f2bf((a3 * c4.w - b3 * s4.w) * sc);
  rb.x = f2bf((b0 * c4.x + a0 * s4.x) * sc);
  rb.y = f2bf((b1 * c4.y + a1 * s4.y) * sc);
  rb.z = f2bf((b2 * c4.z + a2 * s4.z) * sc);
  rb.w = f2bf((b3 * c4.w + a3 * s4.w) * sc);
  *(ushort4*)(base)      = ra;
  *(ushort4*)(base + 32) = rb;
}

// ---- V pre-transpose WITH quad-interleave (slot-consistent with swapped-QK^T P regs) ----
__global__ __launch_bounds__(256) void k_vt(const unsigned short* __restrict__ qkv,
                                            unsigned short* __restrict__ vt){
  __shared__ unsigned short tl[64][66];   // [t][d]
  int head = blockIdx.y;
  int b = head >> 3, kvh = head & 7;
  int t0 = blockIdx.x * 64;
  int t = threadIdx.x;
  int r = t >> 2, cc = (t & 3) << 4;
  const unsigned short* p = qkv + (size_t)(b * Tn + t0 + r) * NQKV + 2560 + kvh * 64 + cc;
  U16x8 v0 = *(const U16x8*)(p);
  U16x8 v1 = *(const U16x8*)(p + 8);
  #pragma unroll
  for (int j = 0; j < 8; ++j) { tl[r][cc + j] = v0.s[j]; tl[r][cc + 8 + j] = v1.s[j]; }
  __syncthreads();
  int d = t >> 2, cpair = t & 3;
  unsigned short* q = vt + ((size_t)head * 64 + d) * Tn + t0;
  #pragma unroll
  for (int ci = 0; ci < 2; ++ci) {
    int c = cpair * 2 + ci;
    U16x8 oo;
    #pragma unroll
    for (int e = 0; e < 8; ++e)
      oo.s[e] = tl[32 * (c >> 2) + 16 * (e >> 2) + 4 * (c & 3) + (e & 3)][d];
    *(U16x8*)(q + c * 8) = oo;
  }
}

// ---- flash attention: QBLK=128 (4 waves x 32 q-rows), KVBLK=64, swapped QK^T,
//      fixed softmax origin (m=0, exp2 domain), P in registers, per-lane l with
//      deferred cross-lane reduction, double-buffered K/V, setprio on MFMA ----
__global__ __launch_bounds__(256) void k_attn(const unsigned short* __restrict__ qkv,
                                              const unsigned short* __restrict__ vt,
                                              unsigned short* __restrict__ y){
  __shared__ unsigned short Ks[2][64 * 64];
  __shared__ unsigned short Vs[2][64 * 64];   // quad-interleaved Vt tile: [d][kv-perm]
  int tid = threadIdx.x, w = tid >> 6, ln = tid & 63, lq = ln & 15, lg = ln >> 4;
  int bh = blockIdx.y, b = bh >> 5, h = bh & 31, kvh = h >> 2;
  int q0 = blockIdx.x * 128;
  // Q fragments straight from global
  frag8 qF[2][2];
  #pragma unroll
  for (int s = 0; s < 2; ++s) {
    const unsigned short* qrow = qkv + (size_t)(b * Tn + q0 + w * 32 + 16 * s + lq) * NQKV + h * 64;
    qF[s][0] = *(const frag8*)(qrow + lg * 8);
    qF[s][1] = *(const frag8*)(qrow + 32 + lg * 8);
  }
  // per-lane staging pointers (source-side chunk swizzle, linear LDS dest)
  int n0 = tid, n1 = 256 + tid;
  int r0 = n0 >> 3, c0 = (n0 & 7) ^ (r0 & 7);
  int r1 = n1 >> 3, c1 = (n1 & 7) ^ (r1 & 7);
  const unsigned short* kp0 = qkv + (size_t)b * Tn * NQKV + 2048 + kvh * 64 + (size_t)r0 * NQKV + c0 * 8;
  const unsigned short* kp1 = qkv + (size_t)b * Tn * NQKV + 2048 + kvh * 64 + (size_t)r1 * NQKV + c1 * 8;
  const unsigned short* vp0 = vt + ((size_t)(b * 8 + kvh) * 64 + r0) * Tn + c0 * 8;
  const unsigned short* vp1 = vt + ((size_t)(b * 8 + kvh) * 64 + r1) * Tn + c1 * 8;
  // per-lane LDS fragment byte offsets (kt-invariant; row&7 == lq&7)
  int koff0 = lq * 128 + (((lg)     ^ (lq & 7)) << 4);
  int koff1 = lq * 128 + (((lg + 4) ^ (lq & 7)) << 4);

#define STAGE(BUF) do {                                      \
    gld16(kp0, (char*)&Ks[BUF][0] + n0 * 16);                \
    gld16(kp1, (char*)&Ks[BUF][0] + n1 * 16);                \
    gld16(vp0, (char*)&Vs[BUF][0] + n0 * 16);                \
    gld16(vp1, (char*)&Vs[BUF][0] + n1 * 16);                \
    kp0 += 64 * NQKV; kp1 += 64 * NQKV; vp0 += 64; vp1 += 64;\
  } while (0)

#define PB(S, KK) ({ union { unsigned u[4]; frag8 f; } t_;                        \
    t_.u[0] = pu[S][2*(KK)][0]; t_.u[1] = pu[S][2*(KK)][1];                       \
    t_.u[2] = pu[S][2*(KK)+1][0]; t_.u[3] = pu[S][2*(KK)+1][1]; t_.f; })

#define COMPUTE(BUF) do {                                                         \
    const char* kb_ = (const char*)&Ks[BUF][0];                                   \
    const char* vb_ = (const char*)&Vs[BUF][0];                                   \
    frag8 kf[4][2];                                                               \
    _Pragma("unroll")                                                             \
    for (int mf = 0; mf < 4; ++mf) {                                              \
      kf[mf][0] = *(const frag8*)(kb_ + mf * 2048 + koff0);                       \
      kf[mf][1] = *(const frag8*)(kb_ + mf * 2048 + koff1);                       \
    }                                                                             \
    fx4 sf[2][4];                                                                 \
    __builtin_amdgcn_s_setprio(1);                                                \
    _Pragma("unroll")                                                             \
    for (int s = 0; s < 2; ++s)                                                   \
      _Pragma("unroll")                                                           \
      for (int mf = 0; mf < 4; ++mf) {                                            \
        sf[s][mf] = (fx4){0.f, 0.f, 0.f, 0.f};                                    \
        sf[s][mf] = MFMA(kf[mf][0], qF[s][0], sf[s][mf]);                         \
        sf[s][mf] = MFMA(kf[mf][1], qF[s][1], sf[s][mf]);                         \
      }                                                                           \
    __builtin_amdgcn_s_setprio(0);                                                \
    unsigned pu[2][4][2];                                                         \
    _Pragma("unroll")                                                             \
    for (int s = 0; s < 2; ++s) {                                                 \
      float ps = 0.f;                                                             \
      _Pragma("unroll")                                                           \
      for (int mf = 0; mf < 4; ++mf) {                                            \
        float p0 = sexp2(sf[s][mf][0]);                                           \
        float p1 = sexp2(sf[s][mf][1]);                                           \
        float p2 = sexp2(sf[s][mf][2]);                                           \
        float p3 = sexp2(sf[s][mf][3]);                                           \
        ps += (p0 + p1) + (p2 + p3);                                              \
        pu[s][mf][0] = cvtpk(p0, p1);                                             \
        pu[s][mf][1] = cvtpk(p2, p3);                                             \
      }                                                                           \
      lpart[s] += ps;                                                             \
    }                                                                             \
    frag8 vf[4][2];                                                               \
    _Pragma("unroll")                                                             \
    for (int df = 0; df < 4; ++df) {                                              \
      vf[df][0] = *(const frag8*)(vb_ + df * 2048 + koff0);                       \
      vf[df][1] = *(const frag8*)(vb_ + df * 2048 + koff1);                       \
    }                                                                             \
    __builtin_amdgcn_s_setprio(1);                                                \
    _Pragma("unroll")                                                             \
    for (int s = 0; s < 2; ++s)                                                   \
      _Pragma("unroll")                                                           \
      for (int df = 0; df < 4; ++df) {                                            \
        o[s][df] = MFMA(vf[df][0], PB(s, 0), o[s][df]);                           \
        o[s][df] = MFMA(vf[df][1], PB(s, 1), o[s][df]);                           \
      }                                                                           \
    __builtin_amdgcn_s_setprio(0);                                                \
  } while (0)

  fx4 o[2][4];
  float lpart[2] = {0.f, 0.f};
  #pragma unroll
  for (int s = 0; s < 2; ++s)
    #pragma unroll
    for (int i = 0; i < 4; ++i) o[s][i] = (fx4){0.f, 0.f, 0.f, 0.f};

  STAGE(0);                 // tile 0 -> buf0
  __syncthreads();          // drain stage(0)
  for (int kt = 0; kt < 32; kt += 2) {
    STAGE(1);               // tile kt+1 -> buf1
    COMPUTE(0);             // tile kt
    __syncthreads();
    if (kt + 2 < 32) STAGE(0);   // tile kt+2 -> buf0
    COMPUTE(1);             // tile kt+1
    __syncthreads();
  }
#undef STAGE
#undef COMPUTE
#undef PB

  // deferred cross-lane l reduction: lanes {lq, lq^16, lq^32, lq^48} partition kv
  #pragma unroll
  for (int s = 0; s < 2; ++s) {
    lpart[s] += __shfl_xor(lpart[s], 16);
    lpart[s] += __shfl_xor(lpart[s], 32);
    float inv = 1.0f / lpart[s];
    unsigned short* yp = y + (size_t)(b * Tn + q0 + w * 32 + 16 * s + lq) * Cn + h * 64;
    #pragma unroll
    for (int df = 0; df < 4; ++df) {
      unsigned lo = cvtpk(o[s][df][0] * inv, o[s][df][1] * inv);
      unsigned hi = cvtpk(o[s][df][2] * inv, o[s][df][3] * inv);
      *(uint2*)(yp + df * 16 + lg * 4) = make_uint2(lo, hi);
    }
  }
}

extern "C" void kernel_launch(void* const* d_in, const int* in_sizes, int n_in,
                              void* d_out, int out_size, void* d_ws, size_t ws_size,
                              hipStream_t stream){
  const float* x  = (const float*)d_in[0];
  const float* Wq = (const float*)d_in[1];
  const float* Wk = (const float*)d_in[2];
  const float* Wv = (const float*)d_in[3];
  const float* Wo = (const float*)d_in[4];
  char* ws = (char*)d_ws;
  size_t off = 0;
  unsigned short* xb    = (unsigned short*)(ws + off); off += (size_t)MR * KD * 2;
  unsigned short* wqkvt = (unsigned short*)(ws + off); off += (size_t)NQKV * KD * 2;
  unsigned short* wot   = (unsigned short*)(ws + off); off += (size_t)KD * KD * 2;
  unsigned short* qkv   = (unsigned short*)(ws + off); off += (size_t)MR * NQKV * 2;
  unsigned short* vtb   = (unsigned short*)(ws + off); off += (size_t)16 * 64 * Tn * 2;
  float* ctab = (float*)(ws + off); off += (size_t)Tn * 32 * 4;
  float* stab = (float*)(ws + off); off += (size_t)Tn * 32 * 4;
  unsigned short* yb = xb;  // xb dead after GEMM1 -> reuse as attention output

  k_cvt<<<8192, 256, 0, stream>>>(x, xb);
  k_transW<<<dim3(48, 32), 256, 0, stream>>>(Wq, Wk, Wv, wqkvt);
  k_transW<<<dim3(32, 32), 256, 0, stream>>>(Wo, Wo, Wo, wot);
  k_ropetab<<<256, 256, 0, stream>>>(ctab, stab);
  k_gemm<1><<<dim3(NQKV / 128, MR / 128), 256, 0, stream>>>(xb, wqkvt, qkv, MR, NQKV, KD);
  k_rope<<<5120, 256, 0, stream>>>(qkv, ctab, stab);
  k_vt<<<dim3(Tn / 64, 16), 256, 0, stream>>>(qkv, vtb);
  k_attn<<<dim3(Tn / 128, 64), 256, 0, stream>>>(qkv, vtb, yb);
  k_gemm<0><<<dim3(KD / 128, MR / 128), 256, 0, stream>>>(yb, wot, d_out, MR, KD, KD);
}